// Round 14
// baseline (605.763 us; speedup 1.0000x reference)
//
#include <hip/hip_runtime.h>
#include <math.h>

#define NN   20000      // nodes
#define NE   640000     // edges
#define NPADN 20480     // padded node count for scan (multiple of 4096)
#define HH   128        // hidden
#define GG   64         // groups
#define INF_ 1e30f
#define FB2  4096       // persistent blocks for edge_fused

typedef unsigned short u16;
typedef short bf16x8 __attribute__((ext_vector_type(8)));
typedef float f32x4 __attribute__((ext_vector_type(4)));

struct KMap { int colb[12]; };   // XM column base per 32-wide k-block
struct WEnt { const float* W; u16* dst; int K; int skip_at; int skip_amt; };
struct WTab { WEnt e[12]; };

__device__ __forceinline__ u16 f2bf(float x) {
  union { float f; unsigned u; } c; c.f = x;
  unsigned r = c.u + 0x7FFFu + ((c.u >> 16) & 1u);
  return (u16)(r >> 16);
}
__device__ __forceinline__ float bflo(unsigned w) {
  union { unsigned u; float f; } c; c.u = w << 16; return c.f;
}
__device__ __forceinline__ float bfhi(unsigned w) {
  union { unsigned u; float f; } c; c.u = w & 0xFFFF0000u; return c.f;
}

// ---------------- block reduction helpers (blockDim == 128) ----------------
__device__ __forceinline__ float blk_sum(float v, float* red) {
#pragma unroll
  for (int off = 32; off >= 1; off >>= 1) v += __shfl_xor(v, off);
  if ((threadIdx.x & 63) == 0) red[threadIdx.x >> 6] = v;
  __syncthreads();
  float r = red[0] + red[1];
  __syncthreads();
  return r;
}
__device__ __forceinline__ float blk_max(float v, float* red) {
#pragma unroll
  for (int off = 32; off >= 1; off >>= 1) v = fmaxf(v, __shfl_xor(v, off));
  if ((threadIdx.x & 63) == 0) red[threadIdx.x >> 6] = v;
  __syncthreads();
  float r = fmaxf(red[0], red[1]);
  __syncthreads();
  return r;
}

// ---------------- CSR construction ----------------
__global__ void zero_ints(int* p, int n) {
  int i = blockIdx.x * 256 + threadIdx.x;
  if (i < n) p[i] = 0;
}

__global__ void hist_kernel(const int* __restrict__ dst, int* __restrict__ deg) {
  int e = blockIdx.x * 256 + threadIdx.x;
  if (e < NE) atomicAdd(&deg[dst[e]], 1);
}

__global__ void scan_kernel(const int* __restrict__ deg, int* __restrict__ row_start,
                            int* __restrict__ cursor) {
  __shared__ int buf[256];
  __shared__ int carry_s;
  int t = threadIdx.x;
  if (t == 0) carry_s = 0;
  __syncthreads();
  for (int base = 0; base < NPADN; base += 4096) {
    int idx0 = base + t * 16;
    int4 a = *(const int4*)&deg[idx0];
    int4 b = *(const int4*)&deg[idx0 + 4];
    int4 c = *(const int4*)&deg[idx0 + 8];
    int4 d = *(const int4*)&deg[idx0 + 12];
    int x[16] = {a.x,a.y,a.z,a.w, b.x,b.y,b.z,b.w, c.x,c.y,c.z,c.w, d.x,d.y,d.z,d.w};
    int pre[16];
    int run = 0;
#pragma unroll
    for (int j = 0; j < 16; j++) { pre[j] = run; run += x[j]; }
    buf[t] = run;
    __syncthreads();
    int sum = run;
#pragma unroll
    for (int off = 1; off < 256; off <<= 1) {
      int addv = (t >= off) ? buf[t - off] : 0;
      __syncthreads();
      sum += addv;
      buf[t] = sum;
      __syncthreads();
    }
    int excl = sum - run;
    int carry = carry_s;
    int basev = carry + excl;
#pragma unroll
    for (int j = 0; j < 16; j++) {
      int i = idx0 + j;
      if (i < NN) { row_start[i] = basev + pre[j]; cursor[i] = basev + pre[j]; }
    }
    __syncthreads();
    if (t == 255) carry_s = carry + sum;
    __syncthreads();
  }
  if (t == 0) row_start[NN] = carry_s;
}

// eidx[p] = edge id, srcs[p] = src node, CSR (dst-sorted) order
__global__ void scatter_kernel(const int* __restrict__ dst, const int* __restrict__ src,
                               int* __restrict__ cursor, int* __restrict__ eidx,
                               int* __restrict__ srcs) {
  int e = blockIdx.x * 256 + threadIdx.x;
  if (e < NE) {
    int d = dst[e];
    int p = atomicAdd(&cursor[d], 1);
    eidx[p] = e;
    srcs[p] = src[e];
  }
}

// ---------------- fused prepack: XM | ehb | 12 weight packs ----------------
__global__ __launch_bounds__(256) void pack_all(
    const float* __restrict__ kind, const float* __restrict__ ntype,
    const float* __restrict__ eh, u16* __restrict__ XM, u16* __restrict__ ehb,
    WTab wt) {
  int id = blockIdx.x * 256 + threadIdx.x;
  if (id < NN * 128) {                      // XM[:,0:128] = bf16([kind|ntype])
    int n = id >> 7, c = id & 127;
    float v = (c < 64) ? kind[n * 64 + c] : ntype[n * 64 + (c - 64)];
    XM[(size_t)n * 512 + c] = f2bf(v);
    return;
  }
  id -= NN * 128;
  if (id < NE * 8) {                        // ehb = bf16(eh), edge order (streaming)
    int p = id >> 3, l = id & 7;
    const float* r = eh + (size_t)p * 64 + l * 8;
    float4 a = *(const float4*)r;
    float4 b = *(const float4*)(r + 4);
    union { u16 u[8]; uint4 v; } pk;
    pk.u[0] = f2bf(a.x); pk.u[1] = f2bf(a.y); pk.u[2] = f2bf(a.z); pk.u[3] = f2bf(a.w);
    pk.u[4] = f2bf(b.x); pk.u[5] = f2bf(b.y); pk.u[6] = f2bf(b.z); pk.u[7] = f2bf(b.w);
    *(uint4*)&ehb[(size_t)p * 64 + l * 8] = pk.v;
    return;
  }
  id -= NE * 8;
#pragma unroll 1
  for (int t = 0; t < 12; t++) {            // Wt[c][k] = bf16(W[rowmap(k)][c])
    int n = 128 * wt.e[t].K;
    if (id < n) {
      int K = wt.e[t].K;
      int c = id / K, k = id - c * K;
      int row = (k < wt.e[t].skip_at) ? k : k + wt.e[t].skip_amt;
      wt.e[t].dst[id] = f2bf(wt.e[t].W[row * 128 + c]);
      return;
    }
    id -= n;
  }
}

// ---------------- CSR-ordered ehb copy: ehc[p] = ehb[eidx[p]] (bf16) ----------------
// Random 128B-row read + sequential write; amortized over both edge layers.
// Makes edge_fused's ehb stream fully sequential and address-computable (no
// load-dependence), leaving the kv table as the only random gather.
__global__ __launch_bounds__(256) void ehb_gather(const u16* __restrict__ ehb,
                                                  const int* __restrict__ eidx,
                                                  u16* __restrict__ ehc) {
  int t = blockIdx.x * 256 + threadIdx.x;
  int p = t >> 3, l = t & 7;
  if (p < NE) {
    int e = eidx[p];
    *(uint4*)&ehc[(size_t)p * 64 + l * 8] =
        *(const uint4*)&ehb[(size_t)e * 64 + l * 8];
  }
}

// ---------------- MFMA node GEMM (chunk-split over blockIdx.y) ----------------
template <int KSTEPS, bool DO_LN, bool DO_LOGIT>
__global__ __launch_bounds__(256) void mfma_gemm(
    const u16* __restrict__ XM, const u16* __restrict__ Wt, KMap kmap,
    const float* __restrict__ b0, const float* __restrict__ b1, const float* __restrict__ b2,
    float* __restrict__ o0, u16* __restrict__ kvB, u16* __restrict__ outbf,
    const float* __restrict__ ln_g, const float* __restrict__ ln_b,
    const float* __restrict__ gate_w, const float* __restrict__ gate_b,
    float* __restrict__ logit) {
  const int lane = threadIdx.x & 63;
  const int wv = threadIdx.x >> 6;
  const int er = lane & 15, kg = lane >> 4;
  const int row0 = (blockIdx.x * 4 + wv) * 16;
  if (row0 >= NN) return;
  const int chunk = blockIdx.y;
  const int arow = (row0 + er < NN) ? row0 + er : NN - 1;
  constexpr int K = KSTEPS * 32;
  const u16* aptr = XM + (size_t)arow * 512 + kg * 8;
  const u16* wptr = Wt + (size_t)chunk * 128 * K + (size_t)er * K + kg * 8;

  f32x4 acc[8];
#pragma unroll
  for (int i = 0; i < 8; i++) acc[i] = (f32x4){0.f, 0.f, 0.f, 0.f};

#pragma unroll
  for (int ks = 0; ks < KSTEPS; ks++) {
    bf16x8 a = *(const bf16x8*)&aptr[kmap.colb[ks]];
#pragma unroll
    for (int nt = 0; nt < 8; nt++) {
      bf16x8 b = *(const bf16x8*)&wptr[(size_t)nt * 16 * K + ks * 32];
      acc[nt] = __builtin_amdgcn_mfma_f32_16x16x32_bf16(a, b, acc[nt], 0, 0, 0);
    }
  }

  if (!DO_LN) {
    const float* bp = (chunk == 0) ? b0 : (chunk == 1) ? b1 : b2;
#pragma unroll
    for (int t = 0; t < 8; t++) {
      int col = er + 16 * t;
      float bv = bp[col];
#pragma unroll
      for (int r = 0; r < 4; r++) {
        int m = row0 + kg * 4 + r;
        if (m < NN) {
          float val = acc[t][r] + bv;
          if (chunk == 0) o0[(size_t)m * 128 + col] = val;
          else            kvB[(size_t)m * 256 + 2 * col + (chunk - 1)] = f2bf(val);
        }
      }
    }
  } else {
    float g[8], bb[8], gw[8];
#pragma unroll
    for (int t = 0; t < 8; t++) {
      int col = er + 16 * t;
      float bv = b0[col];
#pragma unroll
      for (int r = 0; r < 4; r++) acc[t][r] += bv;
      g[t] = ln_g[col]; bb[t] = ln_b[col];
      if (DO_LOGIT) gw[t] = gate_w[col];
    }
    float gb0 = DO_LOGIT ? gate_b[0] : 0.f;
#pragma unroll
    for (int r = 0; r < 4; r++) {
      float s = 0.f;
#pragma unroll
      for (int t = 0; t < 8; t++) s += acc[t][r];
#pragma unroll
      for (int off = 1; off <= 8; off <<= 1) s += __shfl_xor(s, off);
      float mean = s * (1.0f / 128.0f);
      float v = 0.f;
#pragma unroll
      for (int t = 0; t < 8; t++) { float d = acc[t][r] - mean; v = fmaf(d, d, v); }
#pragma unroll
      for (int off = 1; off <= 8; off <<= 1) v += __shfl_xor(v, off);
      float rstd = 1.0f / sqrtf(v * (1.0f / 128.0f) + 1e-5f);
      int m = row0 + kg * 4 + r;
      float lg = 0.f;
      float hv[8];
#pragma unroll
      for (int t = 0; t < 8; t++) {
        hv[t] = (acc[t][r] - mean) * rstd * g[t] + bb[t];
        if (DO_LOGIT) lg = fmaf(hv[t], gw[t], lg);
      }
      if (m < NN) {
        if (outbf) {
#pragma unroll
          for (int t = 0; t < 8; t++) outbf[(size_t)m * 512 + er + 16 * t] = f2bf(hv[t]);
        } else {
#pragma unroll
          for (int t = 0; t < 8; t++) o0[(size_t)m * 128 + er + 16 * t] = hv[t];
        }
      }
      if (DO_LOGIT) {
#pragma unroll
        for (int off = 1; off <= 8; off <<= 1) lg += __shfl_xor(lg, off);
        if (er == 0 && m < NN) logit[m] = lg + gb0;
      }
    }
  }
}

// ---------------- fused edge projection + softmax, 3-deep pipeline ----------------
// r10-verified structure ((256,3), VGPR~80). Change vs r10: ehc is CSR-ordered
// so PEHB's address is pure ALU (rs+16t+er) — sequential per-node stream, no
// se dependence. Only the kv gather remains random. srcs is a plain int array.
#define PIDX(S, t_) { \
    int pp = rs + (t_) * 16 + er; \
    int lv = (pp < re) ? 1 : 0; \
    int pq = lv ? pp : re - 1; \
    pcv##S = pq < 0 ? 0 : pq; \
    pmN##S = lv ? 1.f : 0.f; \
    srcv##S = srcs[pcv##S]; }

#define PEHB(S) { \
    const u16* ep_ = ehc + (size_t)pcv##S * 64 + kg * 8; \
    bE0##S = *(const bf16x8*)&ep_[0]; \
    bE1##S = *(const bf16x8*)&ep_[32]; }

#define PGKV(S) { \
    const u16* kp_ = kvb + (size_t)srcv##S * 256 + 2 * cbase; \
    kv0##S = *(const uint4*)&kp_[0]; \
    kv1##S = *(const uint4*)&kp_[32]; }

#define PCOMP(S) { \
    f32x4 cK0 = {0.f,0.f,0.f,0.f}, cK1 = {0.f,0.f,0.f,0.f}; \
    f32x4 cV0 = {0.f,0.f,0.f,0.f}, cV1 = {0.f,0.f,0.f,0.f}; \
    cK0 = __builtin_amdgcn_mfma_f32_16x16x32_bf16(aK00, bE0##S, cK0, 0, 0, 0); \
    cK0 = __builtin_amdgcn_mfma_f32_16x16x32_bf16(aK01, bE1##S, cK0, 0, 0, 0); \
    cK1 = __builtin_amdgcn_mfma_f32_16x16x32_bf16(aK10, bE0##S, cK1, 0, 0, 0); \
    cK1 = __builtin_amdgcn_mfma_f32_16x16x32_bf16(aK11, bE1##S, cK1, 0, 0, 0); \
    cV0 = __builtin_amdgcn_mfma_f32_16x16x32_bf16(aV00, bE0##S, cV0, 0, 0, 0); \
    cV0 = __builtin_amdgcn_mfma_f32_16x16x32_bf16(aV01, bE1##S, cV0, 0, 0, 0); \
    cV1 = __builtin_amdgcn_mfma_f32_16x16x32_bf16(aV10, bE0##S, cV1, 0, 0, 0); \
    cV1 = __builtin_amdgcn_mfma_f32_16x16x32_bf16(aV11, bE1##S, cV1, 0, 0, 0); \
    float pm = pmC##S; \
    float kk, vv, pe; \
    kk = bflo(kv0##S.x) + cK0[0]; vv = bfhi(kv0##S.x) + cV0[0]; \
    pe = __expf(q0v.x * kk) * pm; S0[0] += pe; H0[0] = fmaf(pe, vv, H0[0]); \
    kk = bflo(kv0##S.y) + cK0[1]; vv = bfhi(kv0##S.y) + cV0[1]; \
    pe = __expf(q0v.y * kk) * pm; S0[1] += pe; H0[1] = fmaf(pe, vv, H0[1]); \
    kk = bflo(kv0##S.z) + cK0[2]; vv = bfhi(kv0##S.z) + cV0[2]; \
    pe = __expf(q0v.z * kk) * pm; S0[2] += pe; H0[2] = fmaf(pe, vv, H0[2]); \
    kk = bflo(kv0##S.w) + cK0[3]; vv = bfhi(kv0##S.w) + cV0[3]; \
    pe = __expf(q0v.w * kk) * pm; S0[3] += pe; H0[3] = fmaf(pe, vv, H0[3]); \
    kk = bflo(kv1##S.x) + cK1[0]; vv = bfhi(kv1##S.x) + cV1[0]; \
    pe = __expf(q1v.x * kk) * pm; S1[0] += pe; H1[0] = fmaf(pe, vv, H1[0]); \
    kk = bflo(kv1##S.y) + cK1[1]; vv = bfhi(kv1##S.y) + cV1[1]; \
    pe = __expf(q1v.y * kk) * pm; S1[1] += pe; H1[1] = fmaf(pe, vv, H1[1]); \
    kk = bflo(kv1##S.z) + cK1[2]; vv = bfhi(kv1##S.z) + cV1[2]; \
    pe = __expf(q1v.z * kk) * pm; S1[2] += pe; H1[2] = fmaf(pe, vv, H1[2]); \
    kk = bflo(kv1##S.w) + cK1[3]; vv = bfhi(kv1##S.w) + cV1[3]; \
    pe = __expf(q1v.w * kk) * pm; S1[3] += pe; H1[3] = fmaf(pe, vv, H1[3]); }

__global__ __launch_bounds__(256, 3) void edge_fused(
    const u16* __restrict__ ehc, const int* __restrict__ srcs,
    const int* __restrict__ row_start,
    const u16* __restrict__ WtK, const u16* __restrict__ WtV,
    const float* __restrict__ qn, const u16* __restrict__ kvb,
    u16* __restrict__ xmh) {
  const int lane = threadIdx.x & 63;
  const int qw = threadIdx.x >> 6;       // channel quarter 0..3
  const int er = lane & 15, kg = lane >> 4;
  const int cbase = qw * 32 + kg * 4;

  // weight A-fragments (round-2-validated layout)
  bf16x8 aK00, aK01, aK10, aK11, aV00, aV01, aV10, aV11;
  {
    int r0 = (qw * 2 + 0) * 16 + er;
    int r1 = (qw * 2 + 1) * 16 + er;
    aK00 = *(const bf16x8*)&WtK[r0 * 64 + kg * 8];
    aK01 = *(const bf16x8*)&WtK[r0 * 64 + 32 + kg * 8];
    aK10 = *(const bf16x8*)&WtK[r1 * 64 + kg * 8];
    aK11 = *(const bf16x8*)&WtK[r1 * 64 + 32 + kg * 8];
    aV00 = *(const bf16x8*)&WtV[r0 * 64 + kg * 8];
    aV01 = *(const bf16x8*)&WtV[r0 * 64 + 32 + kg * 8];
    aV10 = *(const bf16x8*)&WtV[r1 * 64 + kg * 8];
    aV11 = *(const bf16x8*)&WtV[r1 * 64 + 32 + kg * 8];
  }

  for (int n = blockIdx.x; n < NN; n += FB2) {
    const int rs = row_start[n], re = row_start[n + 1];
    const int T2 = (re - rs + 15) >> 4;
    float4 q0v = *(const float4*)&qn[(size_t)n * 128 + cbase];
    float4 q1v = *(const float4*)&qn[(size_t)n * 128 + cbase + 16];
    f32x4 S0 = {0.f,0.f,0.f,0.f}, S1 = {0.f,0.f,0.f,0.f};
    f32x4 H0 = {0.f,0.f,0.f,0.f}, H1 = {0.f,0.f,0.f,0.f};

    int pcvX, srcvX, pcvY, srcvY, pcvZ, srcvZ;
    float pmNX, pmCX, pmNY, pmCY, pmNZ, pmCZ;
    bf16x8 bE0X, bE1X, bE0Y, bE1Y, bE0Z, bE1Z;
    uint4 kv0X, kv1X, kv0Y, kv1Y, kv0Z, kv1Z;

    // prologue: tiles 0,1,2
    PIDX(X, 0); pmCX = pmNX; PEHB(X); PGKV(X);
    PIDX(Y, 1); pmCY = pmNY; PEHB(Y); PGKV(Y);
    PIDX(Z, 2); pmCZ = pmNZ; PEHB(Z); PGKV(Z);

    for (int t = 0; t < T2; t += 3) {
      PIDX(X, t + 3); PCOMP(X); pmCX = pmNX; PEHB(X); PGKV(X);
      PIDX(Y, t + 4); PCOMP(Y); pmCY = pmNY; PEHB(Y); PGKV(Y);
      PIDX(Z, t + 5); PCOMP(Z); pmCZ = pmNZ; PEHB(Z); PGKV(Z);
    }

    // reduce over the 16 er-lanes
#pragma unroll
    for (int off = 1; off <= 8; off <<= 1) {
#pragma unroll
      for (int j = 0; j < 4; j++) {
        S0[j] += __shfl_xor(S0[j], off);
        H0[j] += __shfl_xor(H0[j], off);
        S1[j] += __shfl_xor(S1[j], off);
        H1[j] += __shfl_xor(H1[j], off);
      }
    }
    if (er == 0) {
      uint2 p0, p1;
      if (re > rs) {
        p0.x = (unsigned)f2bf(H0[0]/S0[0]) | ((unsigned)f2bf(H0[1]/S0[1]) << 16);
        p0.y = (unsigned)f2bf(H0[2]/S0[2]) | ((unsigned)f2bf(H0[3]/S0[3]) << 16);
        p1.x = (unsigned)f2bf(H1[0]/S1[0]) | ((unsigned)f2bf(H1[1]/S1[1]) << 16);
        p1.y = (unsigned)f2bf(H1[2]/S1[2]) | ((unsigned)f2bf(H1[3]/S1[3]) << 16);
      } else { p0.x = p0.y = p1.x = p1.y = 0u; }
      *(uint2*)&xmh[(size_t)n * 512 + cbase] = p0;
      *(uint2*)&xmh[(size_t)n * 512 + cbase + 16] = p1;
    }
  }
}

// ---------------- readout (gstart folded in via binary search) ----------------
__global__ __launch_bounds__(128) void readout_kernel(
    const float* __restrict__ h1, const float* __restrict__ logit,
    const int* __restrict__ gid, float* __restrict__ out) {
  __shared__ float red[2];
  int g = blockIdx.x, tid = threadIdx.x;
  int s0, s1;
  {
    int lo = 0, hi = NN;                       // first i with gid[i] >= g
    while (lo < hi) { int mid = (lo + hi) >> 1; if (gid[mid] < g) lo = mid + 1; else hi = mid; }
    s0 = lo;
    lo = s0; hi = NN;                          // first i with gid[i] >= g+1
    while (lo < hi) { int mid = (lo + hi) >> 1; if (gid[mid] < g + 1) lo = mid + 1; else hi = mid; }
    s1 = lo;
  }

  float mx = -INF_;
  for (int i = s0 + tid; i < s1; i += 128) mx = fmaxf(mx, logit[i]);
  mx = blk_max(mx, red);

  float sum = 0.0f;
  for (int i = s0 + tid; i < s1; i += 128) sum += __expf(logit[i] - mx);
  sum = blk_sum(sum, red);

  float a0 = 0.f, a1 = 0.f, a2 = 0.f, a3 = 0.f;
  int i = s0;
  for (; i + 4 <= s1; i += 4) {
    float w0 = __expf(logit[i + 0] - mx);
    float w1 = __expf(logit[i + 1] - mx);
    float w2 = __expf(logit[i + 2] - mx);
    float w3 = __expf(logit[i + 3] - mx);
    a0 = fmaf(w0, h1[(size_t)(i + 0) * 128 + tid], a0);
    a1 = fmaf(w1, h1[(size_t)(i + 1) * 128 + tid], a1);
    a2 = fmaf(w2, h1[(size_t)(i + 2) * 128 + tid], a2);
    a3 = fmaf(w3, h1[(size_t)(i + 3) * 128 + tid], a3);
  }
  for (; i < s1; i++) {
    float w = __expf(logit[i] - mx);
    a0 = fmaf(w, h1[(size_t)i * 128 + tid], a0);
  }
  float acc = (a0 + a1) + (a2 + a3);
  out[g * 128 + tid] = (s1 > s0) ? (acc / sum) : 0.0f;
}

// ---------------- launcher ----------------
extern "C" void kernel_launch(void* const* d_in, const int* in_sizes, int n_in,
                              void* d_out, int out_size, void* d_ws, size_t ws_size,
                              hipStream_t stream) {
  const float* kind  = (const float*)d_in[0];
  const float* ntype = (const float*)d_in[1];
  const float* eh    = (const float*)d_in[2];
  const float* Qw = (const float*)d_in[3];  const float* Qb = (const float*)d_in[4];
  const float* Kw = (const float*)d_in[5];  const float* Kb = (const float*)d_in[6];
  const float* Vw = (const float*)d_in[7];  const float* Vb = (const float*)d_in[8];
  const float* Ww = (const float*)d_in[9];  const float* Wb = (const float*)d_in[10];
  const float* Q2w = (const float*)d_in[11]; const float* Q2b = (const float*)d_in[12];
  const float* K2w = (const float*)d_in[13]; const float* K2b = (const float*)d_in[14];
  const float* V2w = (const float*)d_in[15]; const float* V2b = (const float*)d_in[16];
  const float* W2w = (const float*)d_in[17]; const float* W2b = (const float*)d_in[18];
  const float* ln_g = (const float*)d_in[19]; const float* ln_b = (const float*)d_in[20];
  const float* gate_w = (const float*)d_in[21]; const float* gate_b = (const float*)d_in[22];
  const int* src = (const int*)d_in[23];
  const int* dst = (const int*)d_in[24];
  const int* gid = (const int*)d_in[25];
  float* out = (float*)d_out;

  char* wp = (char*)d_ws;
  auto alloc = [&](size_t bytes) {
    void* p = (void*)wp;
    wp += (bytes + 255) & ~(size_t)255;
    return p;
  };
  u16* XM  = (u16*)alloc((size_t)NN * 512 * 2);   // [kind|ntype | hn | h | hn2] bf16
  u16* ehb = (u16*)alloc((size_t)NE * 64 * 2);    // edge-order bf16 eh
  u16* ehc = (u16*)alloc((size_t)NE * 64 * 2);    // CSR-order bf16 eh
  float* qA = (float*)alloc((size_t)NN * HH * 4);
  u16* kvB = (u16*)alloc((size_t)NN * 256 * 2);   // interleaved k/v bf16
  float* h1 = (float*)alloc((size_t)NN * HH * 4);
  float* logit = (float*)alloc((size_t)NN * 4);
  u16* Wt1 = (u16*)alloc((size_t)384 * 128 * 2);
  u16* Wt2 = (u16*)alloc((size_t)128 * 256 * 2);
  u16* Wt3 = (u16*)alloc((size_t)384 * 256 * 2);
  u16* Wt4 = (u16*)alloc((size_t)128 * 384 * 2);
  u16* WtK1 = (u16*)alloc((size_t)128 * 64 * 2);
  u16* WtV1 = (u16*)alloc((size_t)128 * 64 * 2);
  u16* WtK2 = (u16*)alloc((size_t)128 * 64 * 2);
  u16* WtV2 = (u16*)alloc((size_t)128 * 64 * 2);
  int* deg       = (int*)alloc((size_t)NPADN * 4);
  int* row_start = (int*)alloc((size_t)(NN + 1) * 4);
  int* cursor    = (int*)alloc((size_t)NN * 4);
  int* eidx      = (int*)alloc((size_t)NE * 4);
  int* srcs      = (int*)alloc((size_t)NE * 4);

  const int NB = 1 << 30;  // no skip

  // CSR
  zero_ints<<<(NPADN + 255) / 256, 256, 0, stream>>>(deg, NPADN);
  hist_kernel<<<(NE + 255) / 256, 256, 0, stream>>>(dst, deg);
  scan_kernel<<<1, 256, 0, stream>>>(deg, row_start, cursor);
  scatter_kernel<<<(NE + 255) / 256, 256, 0, stream>>>(dst, src, cursor, eidx, srcs);

  // fused prepack (XM, ehb, all weight transposes)
  WTab wt;
  wt.e[0]  = {Qw,             Wt1,                 128, NB, 0};
  wt.e[1]  = {Kw,             Wt1 + 128 * 128,     128, NB, 0};
  wt.e[2]  = {Vw,             Wt1 + 2 * 128 * 128, 128, NB, 0};
  wt.e[3]  = {Ww,             Wt2,                 256, NB, 0};
  wt.e[4]  = {Q2w,            Wt3,                 256, NB, 0};
  wt.e[5]  = {K2w,            Wt3 + 128 * 256,     256, 128, 64};
  wt.e[6]  = {V2w,            Wt3 + 2 * 128 * 256, 256, 128, 64};
  wt.e[7]  = {W2w,            Wt4,                 384, NB, 0};
  wt.e[8]  = {Kw + 128 * 128, WtK1,                64,  NB, 0};
  wt.e[9]  = {Vw + 128 * 128, WtV1,                64,  NB, 0};
  wt.e[10] = {K2w + 128 * 128, WtK2,               64,  NB, 0};
  wt.e[11] = {V2w + 128 * 128, WtV2,               64,  NB, 0};
  const long long PACK_ITEMS = (long long)NN * 128 + (long long)NE * 8 + 262144;
  pack_all<<<(int)((PACK_ITEMS + 255) / 256), 256, 0, stream>>>(
      kind, ntype, eh, XM, ehb, wt);

  // CSR-ordered bf16 eh copy (amortized over both edge layers)
  ehb_gather<<<(NE * 8 + 255) / 256, 256, 0, stream>>>(ehb, eidx, ehc);

  KMap km1{}, km2{}, km3{}, km4{};
  for (int b = 0; b < 4; b++)  km1.colb[b] = 32 * b;                       // [kind|ntype]
  for (int b = 0; b < 8; b++)  km2.colb[b] = (b < 4) ? 128 + 32 * b : 32 * (b - 4);   // [hn | kind|ntype]
  for (int b = 0; b < 8; b++)  km3.colb[b] = (b < 4) ? 32 * b : 256 + 32 * (b - 4);   // [kind|ntype | h]
  for (int b = 0; b < 12; b++) km4.colb[b] = (b < 4) ? 384 + 32 * b
                                       : (b < 8) ? 256 + 32 * (b - 4) : 32 * (b - 8); // [hn2 | h | kind|ntype]

  const int GB = (NN + 63) / 64;

  // ---- layer 1 ----
  mfma_gemm<4, false, false><<<dim3(GB, 3), 256, 0, stream>>>(
      XM, Wt1, km1, Qb, Kb, Vb, qA, kvB, nullptr,
      nullptr, nullptr, nullptr, nullptr, nullptr);

  edge_fused<<<FB2, 256, 0, stream>>>(ehc, srcs, row_start, WtK1, WtV1,
                                      qA, kvB, XM + 128);

  mfma_gemm<8, true, false><<<dim3(GB, 1), 256, 0, stream>>>(
      XM, Wt2, km2, Wb, nullptr, nullptr, nullptr, nullptr, XM + 256,
      ln_g, ln_b, nullptr, nullptr, nullptr);

  // ---- layer 2 ----
  mfma_gemm<8, false, false><<<dim3(GB, 3), 256, 0, stream>>>(
      XM, Wt3, km3, Q2b, K2b, V2b, qA, kvB, nullptr,
      nullptr, nullptr, nullptr, nullptr, nullptr);

  edge_fused<<<FB2, 256, 0, stream>>>(ehc, srcs, row_start, WtK2, WtV2,
                                      qA, kvB, XM + 384);

  mfma_gemm<12, true, true><<<dim3(GB, 1), 256, 0, stream>>>(
      XM, Wt4, km4, W2b, nullptr, nullptr, h1, nullptr, nullptr,
      ln_g, ln_b, gate_w, gate_b, logit);

  // readout (gstart computed in-kernel)
  readout_kernel<<<GG, 128, 0, stream>>>(h1, logit, gid, out);
}

// Round 15
// 564.600 us; speedup vs baseline: 1.0729x; 1.0729x over previous
//
#include <hip/hip_runtime.h>
#include <math.h>

#define NN   20000      // nodes
#define NE   640000     // edges
#define NPADN 20480     // padded node count for scan (multiple of 4096)
#define HH   128        // hidden
#define GG   64         // groups
#define INF_ 1e30f
#define FB2  4096       // persistent blocks for edge_fused

typedef unsigned short u16;
typedef short bf16x8 __attribute__((ext_vector_type(8)));
typedef float f32x4 __attribute__((ext_vector_type(4)));

struct KMap { int colb[12]; };   // XM column base per 32-wide k-block
struct WEnt { const float* W; u16* dst; int K; int skip_at; int skip_amt; };
struct WTab { WEnt e[12]; };

__device__ __forceinline__ u16 f2bf(float x) {
  union { float f; unsigned u; } c; c.f = x;
  unsigned r = c.u + 0x7FFFu + ((c.u >> 16) & 1u);
  return (u16)(r >> 16);
}
__device__ __forceinline__ float bflo(unsigned w) {
  union { unsigned u; float f; } c; c.u = w << 16; return c.f;
}
__device__ __forceinline__ float bfhi(unsigned w) {
  union { unsigned u; float f; } c; c.u = w & 0xFFFF0000u; return c.f;
}

// ---------------- block reduction helpers (blockDim == 128) ----------------
__device__ __forceinline__ float blk_sum(float v, float* red) {
#pragma unroll
  for (int off = 32; off >= 1; off >>= 1) v += __shfl_xor(v, off);
  if ((threadIdx.x & 63) == 0) red[threadIdx.x >> 6] = v;
  __syncthreads();
  float r = red[0] + red[1];
  __syncthreads();
  return r;
}
__device__ __forceinline__ float blk_max(float v, float* red) {
#pragma unroll
  for (int off = 32; off >= 1; off >>= 1) v = fmaxf(v, __shfl_xor(v, off));
  if ((threadIdx.x & 63) == 0) red[threadIdx.x >> 6] = v;
  __syncthreads();
  float r = fmaxf(red[0], red[1]);
  __syncthreads();
  return r;
}

// ---------------- CSR construction ----------------
__global__ void zero_ints(int* p, int n) {
  int i = blockIdx.x * 256 + threadIdx.x;
  if (i < n) p[i] = 0;
}

__global__ void hist_kernel(const int* __restrict__ dst, int* __restrict__ deg) {
  int e = blockIdx.x * 256 + threadIdx.x;
  if (e < NE) atomicAdd(&deg[dst[e]], 1);
}

__global__ void scan_kernel(const int* __restrict__ deg, int* __restrict__ row_start,
                            int* __restrict__ cursor) {
  __shared__ int buf[256];
  __shared__ int carry_s;
  int t = threadIdx.x;
  if (t == 0) carry_s = 0;
  __syncthreads();
  for (int base = 0; base < NPADN; base += 4096) {
    int idx0 = base + t * 16;
    int4 a = *(const int4*)&deg[idx0];
    int4 b = *(const int4*)&deg[idx0 + 4];
    int4 c = *(const int4*)&deg[idx0 + 8];
    int4 d = *(const int4*)&deg[idx0 + 12];
    int x[16] = {a.x,a.y,a.z,a.w, b.x,b.y,b.z,b.w, c.x,c.y,c.z,c.w, d.x,d.y,d.z,d.w};
    int pre[16];
    int run = 0;
#pragma unroll
    for (int j = 0; j < 16; j++) { pre[j] = run; run += x[j]; }
    buf[t] = run;
    __syncthreads();
    int sum = run;
#pragma unroll
    for (int off = 1; off < 256; off <<= 1) {
      int addv = (t >= off) ? buf[t - off] : 0;
      __syncthreads();
      sum += addv;
      buf[t] = sum;
      __syncthreads();
    }
    int excl = sum - run;
    int carry = carry_s;
    int basev = carry + excl;
#pragma unroll
    for (int j = 0; j < 16; j++) {
      int i = idx0 + j;
      if (i < NN) { row_start[i] = basev + pre[j]; cursor[i] = basev + pre[j]; }
    }
    __syncthreads();
    if (t == 255) carry_s = carry + sum;
    __syncthreads();
  }
  if (t == 0) row_start[NN] = carry_s;
}

// pos[e] = CSR slot of edge e; srcs[p] = src node at CSR slot p
__global__ void scatter_kernel(const int* __restrict__ dst, const int* __restrict__ src,
                               int* __restrict__ cursor, int* __restrict__ pos,
                               int* __restrict__ srcs) {
  int e = blockIdx.x * 256 + threadIdx.x;
  if (e < NE) {
    int d = dst[e];
    int p = atomicAdd(&cursor[d], 1);
    pos[e] = p;
    srcs[p] = src[e];
  }
}

// ---------------- fused prepack: XM | ehc (CSR-scattered write) | 12 weight packs ----------------
// eh is read SEQUENTIALLY; the bf16 row is written to its CSR slot pos[e]
// (scattered 128B-row write — fire-and-forget, no latency stall). This gives
// edge_fused a fully sequential ehc stream with no extra gather kernel.
__global__ __launch_bounds__(256) void pack_all(
    const float* __restrict__ kind, const float* __restrict__ ntype,
    const float* __restrict__ eh, const int* __restrict__ pos,
    u16* __restrict__ XM, u16* __restrict__ ehc, WTab wt) {
  int id = blockIdx.x * 256 + threadIdx.x;
  if (id < NN * 128) {                      // XM[:,0:128] = bf16([kind|ntype])
    int n = id >> 7, c = id & 127;
    float v = (c < 64) ? kind[n * 64 + c] : ntype[n * 64 + (c - 64)];
    XM[(size_t)n * 512 + c] = f2bf(v);
    return;
  }
  id -= NN * 128;
  if (id < NE * 8) {                        // ehc[pos[e]] = bf16(eh[e])
    int e = id >> 3, l = id & 7;
    const float* r = eh + (size_t)e * 64 + l * 8;
    float4 a = *(const float4*)r;
    float4 b = *(const float4*)(r + 4);
    union { u16 u[8]; uint4 v; } pk;
    pk.u[0] = f2bf(a.x); pk.u[1] = f2bf(a.y); pk.u[2] = f2bf(a.z); pk.u[3] = f2bf(a.w);
    pk.u[4] = f2bf(b.x); pk.u[5] = f2bf(b.y); pk.u[6] = f2bf(b.z); pk.u[7] = f2bf(b.w);
    int p = pos[e];
    *(uint4*)&ehc[(size_t)p * 64 + l * 8] = pk.v;
    return;
  }
  id -= NE * 8;
#pragma unroll 1
  for (int t = 0; t < 12; t++) {            // Wt[c][k] = bf16(W[rowmap(k)][c])
    int n = 128 * wt.e[t].K;
    if (id < n) {
      int K = wt.e[t].K;
      int c = id / K, k = id - c * K;
      int row = (k < wt.e[t].skip_at) ? k : k + wt.e[t].skip_amt;
      wt.e[t].dst[id] = f2bf(wt.e[t].W[row * 128 + c]);
      return;
    }
    id -= n;
  }
}

// ---------------- MFMA node GEMM (chunk-split over blockIdx.y) ----------------
template <int KSTEPS, bool DO_LN, bool DO_LOGIT>
__global__ __launch_bounds__(256) void mfma_gemm(
    const u16* __restrict__ XM, const u16* __restrict__ Wt, KMap kmap,
    const float* __restrict__ b0, const float* __restrict__ b1, const float* __restrict__ b2,
    float* __restrict__ o0, u16* __restrict__ kvB, u16* __restrict__ outbf,
    const float* __restrict__ ln_g, const float* __restrict__ ln_b,
    const float* __restrict__ gate_w, const float* __restrict__ gate_b,
    float* __restrict__ logit) {
  const int lane = threadIdx.x & 63;
  const int wv = threadIdx.x >> 6;
  const int er = lane & 15, kg = lane >> 4;
  const int row0 = (blockIdx.x * 4 + wv) * 16;
  if (row0 >= NN) return;
  const int chunk = blockIdx.y;
  const int arow = (row0 + er < NN) ? row0 + er : NN - 1;
  constexpr int K = KSTEPS * 32;
  const u16* aptr = XM + (size_t)arow * 512 + kg * 8;
  const u16* wptr = Wt + (size_t)chunk * 128 * K + (size_t)er * K + kg * 8;

  f32x4 acc[8];
#pragma unroll
  for (int i = 0; i < 8; i++) acc[i] = (f32x4){0.f, 0.f, 0.f, 0.f};

#pragma unroll
  for (int ks = 0; ks < KSTEPS; ks++) {
    bf16x8 a = *(const bf16x8*)&aptr[kmap.colb[ks]];
#pragma unroll
    for (int nt = 0; nt < 8; nt++) {
      bf16x8 b = *(const bf16x8*)&wptr[(size_t)nt * 16 * K + ks * 32];
      acc[nt] = __builtin_amdgcn_mfma_f32_16x16x32_bf16(a, b, acc[nt], 0, 0, 0);
    }
  }

  if (!DO_LN) {
    const float* bp = (chunk == 0) ? b0 : (chunk == 1) ? b1 : b2;
#pragma unroll
    for (int t = 0; t < 8; t++) {
      int col = er + 16 * t;
      float bv = bp[col];
#pragma unroll
      for (int r = 0; r < 4; r++) {
        int m = row0 + kg * 4 + r;
        if (m < NN) {
          float val = acc[t][r] + bv;
          if (chunk == 0) o0[(size_t)m * 128 + col] = val;
          else            kvB[(size_t)m * 256 + 2 * col + (chunk - 1)] = f2bf(val);
        }
      }
    }
  } else {
    float g[8], bb[8], gw[8];
#pragma unroll
    for (int t = 0; t < 8; t++) {
      int col = er + 16 * t;
      float bv = b0[col];
#pragma unroll
      for (int r = 0; r < 4; r++) acc[t][r] += bv;
      g[t] = ln_g[col]; bb[t] = ln_b[col];
      if (DO_LOGIT) gw[t] = gate_w[col];
    }
    float gb0 = DO_LOGIT ? gate_b[0] : 0.f;
#pragma unroll
    for (int r = 0; r < 4; r++) {
      float s = 0.f;
#pragma unroll
      for (int t = 0; t < 8; t++) s += acc[t][r];
#pragma unroll
      for (int off = 1; off <= 8; off <<= 1) s += __shfl_xor(s, off);
      float mean = s * (1.0f / 128.0f);
      float v = 0.f;
#pragma unroll
      for (int t = 0; t < 8; t++) { float d = acc[t][r] - mean; v = fmaf(d, d, v); }
#pragma unroll
      for (int off = 1; off <= 8; off <<= 1) v += __shfl_xor(v, off);
      float rstd = 1.0f / sqrtf(v * (1.0f / 128.0f) + 1e-5f);
      int m = row0 + kg * 4 + r;
      float lg = 0.f;
      float hv[8];
#pragma unroll
      for (int t = 0; t < 8; t++) {
        hv[t] = (acc[t][r] - mean) * rstd * g[t] + bb[t];
        if (DO_LOGIT) lg = fmaf(hv[t], gw[t], lg);
      }
      if (m < NN) {
        if (outbf) {
#pragma unroll
          for (int t = 0; t < 8; t++) outbf[(size_t)m * 512 + er + 16 * t] = f2bf(hv[t]);
        } else {
#pragma unroll
          for (int t = 0; t < 8; t++) o0[(size_t)m * 128 + er + 16 * t] = hv[t];
        }
      }
      if (DO_LOGIT) {
#pragma unroll
        for (int off = 1; off <= 8; off <<= 1) lg += __shfl_xor(lg, off);
        if (er == 0 && m < NN) logit[m] = lg + gb0;
      }
    }
  }
}

// ---------------- fused edge projection + softmax, 3-deep pipeline ----------------
// r14-verified structure (149us, VGPR 84): ehc is CSR-ordered so PEHB's
// address is pure ALU — sequential per-node stream; only the kv gather is
// random. srcs is a plain int array.
#define PIDX(S, t_) { \
    int pp = rs + (t_) * 16 + er; \
    int lv = (pp < re) ? 1 : 0; \
    int pq = lv ? pp : re - 1; \
    pcv##S = pq < 0 ? 0 : pq; \
    pmN##S = lv ? 1.f : 0.f; \
    srcv##S = srcs[pcv##S]; }

#define PEHB(S) { \
    const u16* ep_ = ehc + (size_t)pcv##S * 64 + kg * 8; \
    bE0##S = *(const bf16x8*)&ep_[0]; \
    bE1##S = *(const bf16x8*)&ep_[32]; }

#define PGKV(S) { \
    const u16* kp_ = kvb + (size_t)srcv##S * 256 + 2 * cbase; \
    kv0##S = *(const uint4*)&kp_[0]; \
    kv1##S = *(const uint4*)&kp_[32]; }

#define PCOMP(S) { \
    f32x4 cK0 = {0.f,0.f,0.f,0.f}, cK1 = {0.f,0.f,0.f,0.f}; \
    f32x4 cV0 = {0.f,0.f,0.f,0.f}, cV1 = {0.f,0.f,0.f,0.f}; \
    cK0 = __builtin_amdgcn_mfma_f32_16x16x32_bf16(aK00, bE0##S, cK0, 0, 0, 0); \
    cK0 = __builtin_amdgcn_mfma_f32_16x16x32_bf16(aK01, bE1##S, cK0, 0, 0, 0); \
    cK1 = __builtin_amdgcn_mfma_f32_16x16x32_bf16(aK10, bE0##S, cK1, 0, 0, 0); \
    cK1 = __builtin_amdgcn_mfma_f32_16x16x32_bf16(aK11, bE1##S, cK1, 0, 0, 0); \
    cV0 = __builtin_amdgcn_mfma_f32_16x16x32_bf16(aV00, bE0##S, cV0, 0, 0, 0); \
    cV0 = __builtin_amdgcn_mfma_f32_16x16x32_bf16(aV01, bE1##S, cV0, 0, 0, 0); \
    cV1 = __builtin_amdgcn_mfma_f32_16x16x32_bf16(aV10, bE0##S, cV1, 0, 0, 0); \
    cV1 = __builtin_amdgcn_mfma_f32_16x16x32_bf16(aV11, bE1##S, cV1, 0, 0, 0); \
    float pm = pmC##S; \
    float kk, vv, pe; \
    kk = bflo(kv0##S.x) + cK0[0]; vv = bfhi(kv0##S.x) + cV0[0]; \
    pe = __expf(q0v.x * kk) * pm; S0[0] += pe; H0[0] = fmaf(pe, vv, H0[0]); \
    kk = bflo(kv0##S.y) + cK0[1]; vv = bfhi(kv0##S.y) + cV0[1]; \
    pe = __expf(q0v.y * kk) * pm; S0[1] += pe; H0[1] = fmaf(pe, vv, H0[1]); \
    kk = bflo(kv0##S.z) + cK0[2]; vv = bfhi(kv0##S.z) + cV0[2]; \
    pe = __expf(q0v.z * kk) * pm; S0[2] += pe; H0[2] = fmaf(pe, vv, H0[2]); \
    kk = bflo(kv0##S.w) + cK0[3]; vv = bfhi(kv0##S.w) + cV0[3]; \
    pe = __expf(q0v.w * kk) * pm; S0[3] += pe; H0[3] = fmaf(pe, vv, H0[3]); \
    kk = bflo(kv1##S.x) + cK1[0]; vv = bfhi(kv1##S.x) + cV1[0]; \
    pe = __expf(q1v.x * kk) * pm; S1[0] += pe; H1[0] = fmaf(pe, vv, H1[0]); \
    kk = bflo(kv1##S.y) + cK1[1]; vv = bfhi(kv1##S.y) + cV1[1]; \
    pe = __expf(q1v.y * kk) * pm; S1[1] += pe; H1[1] = fmaf(pe, vv, H1[1]); \
    kk = bflo(kv1##S.z) + cK1[2]; vv = bfhi(kv1##S.z) + cV1[2]; \
    pe = __expf(q1v.z * kk) * pm; S1[2] += pe; H1[2] = fmaf(pe, vv, H1[2]); \
    kk = bflo(kv1##S.w) + cK1[3]; vv = bfhi(kv1##S.w) + cV1[3]; \
    pe = __expf(q1v.w * kk) * pm; S1[3] += pe; H1[3] = fmaf(pe, vv, H1[3]); }

__global__ __launch_bounds__(256, 3) void edge_fused(
    const u16* __restrict__ ehc, const int* __restrict__ srcs,
    const int* __restrict__ row_start,
    const u16* __restrict__ WtK, const u16* __restrict__ WtV,
    const float* __restrict__ qn, const u16* __restrict__ kvb,
    u16* __restrict__ xmh) {
  const int lane = threadIdx.x & 63;
  const int qw = threadIdx.x >> 6;       // channel quarter 0..3
  const int er = lane & 15, kg = lane >> 4;
  const int cbase = qw * 32 + kg * 4;

  // weight A-fragments (round-2-validated layout)
  bf16x8 aK00, aK01, aK10, aK11, aV00, aV01, aV10, aV11;
  {
    int r0 = (qw * 2 + 0) * 16 + er;
    int r1 = (qw * 2 + 1) * 16 + er;
    aK00 = *(const bf16x8*)&WtK[r0 * 64 + kg * 8];
    aK01 = *(const bf16x8*)&WtK[r0 * 64 + 32 + kg * 8];
    aK10 = *(const bf16x8*)&WtK[r1 * 64 + kg * 8];
    aK11 = *(const bf16x8*)&WtK[r1 * 64 + 32 + kg * 8];
    aV00 = *(const bf16x8*)&WtV[r0 * 64 + kg * 8];
    aV01 = *(const bf16x8*)&WtV[r0 * 64 + 32 + kg * 8];
    aV10 = *(const bf16x8*)&WtV[r1 * 64 + kg * 8];
    aV11 = *(const bf16x8*)&WtV[r1 * 64 + 32 + kg * 8];
  }

  for (int n = blockIdx.x; n < NN; n += FB2) {
    const int rs = row_start[n], re = row_start[n + 1];
    const int T2 = (re - rs + 15) >> 4;
    float4 q0v = *(const float4*)&qn[(size_t)n * 128 + cbase];
    float4 q1v = *(const float4*)&qn[(size_t)n * 128 + cbase + 16];
    f32x4 S0 = {0.f,0.f,0.f,0.f}, S1 = {0.f,0.f,0.f,0.f};
    f32x4 H0 = {0.f,0.f,0.f,0.f}, H1 = {0.f,0.f,0.f,0.f};

    int pcvX, srcvX, pcvY, srcvY, pcvZ, srcvZ;
    float pmNX, pmCX, pmNY, pmCY, pmNZ, pmCZ;
    bf16x8 bE0X, bE1X, bE0Y, bE1Y, bE0Z, bE1Z;
    uint4 kv0X, kv1X, kv0Y, kv1Y, kv0Z, kv1Z;

    // prologue: tiles 0,1,2
    PIDX(X, 0); pmCX = pmNX; PEHB(X); PGKV(X);
    PIDX(Y, 1); pmCY = pmNY; PEHB(Y); PGKV(Y);
    PIDX(Z, 2); pmCZ = pmNZ; PEHB(Z); PGKV(Z);

    for (int t = 0; t < T2; t += 3) {
      PIDX(X, t + 3); PCOMP(X); pmCX = pmNX; PEHB(X); PGKV(X);
      PIDX(Y, t + 4); PCOMP(Y); pmCY = pmNY; PEHB(Y); PGKV(Y);
      PIDX(Z, t + 5); PCOMP(Z); pmCZ = pmNZ; PEHB(Z); PGKV(Z);
    }

    // reduce over the 16 er-lanes
#pragma unroll
    for (int off = 1; off <= 8; off <<= 1) {
#pragma unroll
      for (int j = 0; j < 4; j++) {
        S0[j] += __shfl_xor(S0[j], off);
        H0[j] += __shfl_xor(H0[j], off);
        S1[j] += __shfl_xor(S1[j], off);
        H1[j] += __shfl_xor(H1[j], off);
      }
    }
    if (er == 0) {
      uint2 p0, p1;
      if (re > rs) {
        p0.x = (unsigned)f2bf(H0[0]/S0[0]) | ((unsigned)f2bf(H0[1]/S0[1]) << 16);
        p0.y = (unsigned)f2bf(H0[2]/S0[2]) | ((unsigned)f2bf(H0[3]/S0[3]) << 16);
        p1.x = (unsigned)f2bf(H1[0]/S1[0]) | ((unsigned)f2bf(H1[1]/S1[1]) << 16);
        p1.y = (unsigned)f2bf(H1[2]/S1[2]) | ((unsigned)f2bf(H1[3]/S1[3]) << 16);
      } else { p0.x = p0.y = p1.x = p1.y = 0u; }
      *(uint2*)&xmh[(size_t)n * 512 + cbase] = p0;
      *(uint2*)&xmh[(size_t)n * 512 + cbase + 16] = p1;
    }
  }
}

// ---------------- readout (gstart folded in via binary search) ----------------
__global__ __launch_bounds__(128) void readout_kernel(
    const float* __restrict__ h1, const float* __restrict__ logit,
    const int* __restrict__ gid, float* __restrict__ out) {
  __shared__ float red[2];
  int g = blockIdx.x, tid = threadIdx.x;
  int s0, s1;
  {
    int lo = 0, hi = NN;                       // first i with gid[i] >= g
    while (lo < hi) { int mid = (lo + hi) >> 1; if (gid[mid] < g) lo = mid + 1; else hi = mid; }
    s0 = lo;
    lo = s0; hi = NN;                          // first i with gid[i] >= g+1
    while (lo < hi) { int mid = (lo + hi) >> 1; if (gid[mid] < g + 1) lo = mid + 1; else hi = mid; }
    s1 = lo;
  }

  float mx = -INF_;
  for (int i = s0 + tid; i < s1; i += 128) mx = fmaxf(mx, logit[i]);
  mx = blk_max(mx, red);

  float sum = 0.0f;
  for (int i = s0 + tid; i < s1; i += 128) sum += __expf(logit[i] - mx);
  sum = blk_sum(sum, red);

  float a0 = 0.f, a1 = 0.f, a2 = 0.f, a3 = 0.f;
  int i = s0;
  for (; i + 4 <= s1; i += 4) {
    float w0 = __expf(logit[i + 0] - mx);
    float w1 = __expf(logit[i + 1] - mx);
    float w2 = __expf(logit[i + 2] - mx);
    float w3 = __expf(logit[i + 3] - mx);
    a0 = fmaf(w0, h1[(size_t)(i + 0) * 128 + tid], a0);
    a1 = fmaf(w1, h1[(size_t)(i + 1) * 128 + tid], a1);
    a2 = fmaf(w2, h1[(size_t)(i + 2) * 128 + tid], a2);
    a3 = fmaf(w3, h1[(size_t)(i + 3) * 128 + tid], a3);
  }
  for (; i < s1; i++) {
    float w = __expf(logit[i] - mx);
    a0 = fmaf(w, h1[(size_t)i * 128 + tid], a0);
  }
  float acc = (a0 + a1) + (a2 + a3);
  out[g * 128 + tid] = (s1 > s0) ? (acc / sum) : 0.0f;
}

// ---------------- launcher ----------------
extern "C" void kernel_launch(void* const* d_in, const int* in_sizes, int n_in,
                              void* d_out, int out_size, void* d_ws, size_t ws_size,
                              hipStream_t stream) {
  const float* kind  = (const float*)d_in[0];
  const float* ntype = (const float*)d_in[1];
  const float* eh    = (const float*)d_in[2];
  const float* Qw = (const float*)d_in[3];  const float* Qb = (const float*)d_in[4];
  const float* Kw = (const float*)d_in[5];  const float* Kb = (const float*)d_in[6];
  const float* Vw = (const float*)d_in[7];  const float* Vb = (const float*)d_in[8];
  const float* Ww = (const float*)d_in[9];  const float* Wb = (const float*)d_in[10];
  const float* Q2w = (const float*)d_in[11]; const float* Q2b = (const float*)d_in[12];
  const float* K2w = (const float*)d_in[13]; const float* K2b = (const float*)d_in[14];
  const float* V2w = (const float*)d_in[15]; const float* V2b = (const float*)d_in[16];
  const float* W2w = (const float*)d_in[17]; const float* W2b = (const float*)d_in[18];
  const float* ln_g = (const float*)d_in[19]; const float* ln_b = (const float*)d_in[20];
  const float* gate_w = (const float*)d_in[21]; const float* gate_b = (const float*)d_in[22];
  const int* src = (const int*)d_in[23];
  const int* dst = (const int*)d_in[24];
  const int* gid = (const int*)d_in[25];
  float* out = (float*)d_out;

  char* wp = (char*)d_ws;
  auto alloc = [&](size_t bytes) {
    void* p = (void*)wp;
    wp += (bytes + 255) & ~(size_t)255;
    return p;
  };
  u16* XM  = (u16*)alloc((size_t)NN * 512 * 2);   // [kind|ntype | hn | h | hn2] bf16
  u16* ehc = (u16*)alloc((size_t)NE * 64 * 2);    // CSR-order bf16 eh
  float* qA = (float*)alloc((size_t)NN * HH * 4);
  u16* kvB = (u16*)alloc((size_t)NN * 256 * 2);   // interleaved k/v bf16
  float* h1 = (float*)alloc((size_t)NN * HH * 4);
  float* logit = (float*)alloc((size_t)NN * 4);
  u16* Wt1 = (u16*)alloc((size_t)384 * 128 * 2);
  u16* Wt2 = (u16*)alloc((size_t)128 * 256 * 2);
  u16* Wt3 = (u16*)alloc((size_t)384 * 256 * 2);
  u16* Wt4 = (u16*)alloc((size_t)128 * 384 * 2);
  u16* WtK1 = (u16*)alloc((size_t)128 * 64 * 2);
  u16* WtV1 = (u16*)alloc((size_t)128 * 64 * 2);
  u16* WtK2 = (u16*)alloc((size_t)128 * 64 * 2);
  u16* WtV2 = (u16*)alloc((size_t)128 * 64 * 2);
  int* deg       = (int*)alloc((size_t)NPADN * 4);
  int* row_start = (int*)alloc((size_t)(NN + 1) * 4);
  int* cursor    = (int*)alloc((size_t)NN * 4);
  int* pos       = (int*)alloc((size_t)NE * 4);
  int* srcs      = (int*)alloc((size_t)NE * 4);

  const int NB = 1 << 30;  // no skip

  // CSR
  zero_ints<<<(NPADN + 255) / 256, 256, 0, stream>>>(deg, NPADN);
  hist_kernel<<<(NE + 255) / 256, 256, 0, stream>>>(dst, deg);
  scan_kernel<<<1, 256, 0, stream>>>(deg, row_start, cursor);
  scatter_kernel<<<(NE + 255) / 256, 256, 0, stream>>>(dst, src, cursor, pos, srcs);

  // fused prepack (XM, CSR-scattered ehc, all weight transposes)
  WTab wt;
  wt.e[0]  = {Qw,             Wt1,                 128, NB, 0};
  wt.e[1]  = {Kw,             Wt1 + 128 * 128,     128, NB, 0};
  wt.e[2]  = {Vw,             Wt1 + 2 * 128 * 128, 128, NB, 0};
  wt.e[3]  = {Ww,             Wt2,                 256, NB, 0};
  wt.e[4]  = {Q2w,            Wt3,                 256, NB, 0};
  wt.e[5]  = {K2w,            Wt3 + 128 * 256,     256, 128, 64};
  wt.e[6]  = {V2w,            Wt3 + 2 * 128 * 256, 256, 128, 64};
  wt.e[7]  = {W2w,            Wt4,                 384, NB, 0};
  wt.e[8]  = {Kw + 128 * 128, WtK1,                64,  NB, 0};
  wt.e[9]  = {Vw + 128 * 128, WtV1,                64,  NB, 0};
  wt.e[10] = {K2w + 128 * 128, WtK2,               64,  NB, 0};
  wt.e[11] = {V2w + 128 * 128, WtV2,               64,  NB, 0};
  const long long PACK_ITEMS = (long long)NN * 128 + (long long)NE * 8 + 262144;
  pack_all<<<(int)((PACK_ITEMS + 255) / 256), 256, 0, stream>>>(
      kind, ntype, eh, pos, XM, ehc, wt);

  KMap km1{}, km2{}, km3{}, km4{};
  for (int b = 0; b < 4; b++)  km1.colb[b] = 32 * b;                       // [kind|ntype]
  for (int b = 0; b < 8; b++)  km2.colb[b] = (b < 4) ? 128 + 32 * b : 32 * (b - 4);   // [hn | kind|ntype]
  for (int b = 0; b < 8; b++)  km3.colb[b] = (b < 4) ? 32 * b : 256 + 32 * (b - 4);   // [kind|ntype | h]
  for (int b = 0; b < 12; b++) km4.colb[b] = (b < 4) ? 384 + 32 * b
                                       : (b < 8) ? 256 + 32 * (b - 4) : 32 * (b - 8); // [hn2 | h | kind|ntype]

  const int GB = (NN + 63) / 64;

  // ---- layer 1 ----
  mfma_gemm<4, false, false><<<dim3(GB, 3), 256, 0, stream>>>(
      XM, Wt1, km1, Qb, Kb, Vb, qA, kvB, nullptr,
      nullptr, nullptr, nullptr, nullptr, nullptr);

  edge_fused<<<FB2, 256, 0, stream>>>(ehc, srcs, row_start, WtK1, WtV1,
                                      qA, kvB, XM + 128);

  mfma_gemm<8, true, false><<<dim3(GB, 1), 256, 0, stream>>>(
      XM, Wt2, km2, Wb, nullptr, nullptr, nullptr, nullptr, XM + 256,
      ln_g, ln_b, nullptr, nullptr, nullptr);

  // ---- layer 2 ----
  mfma_gemm<8, false, false><<<dim3(GB, 3), 256, 0, stream>>>(
      XM, Wt3, km3, Q2b, K2b, V2b, qA, kvB, nullptr,
      nullptr, nullptr, nullptr, nullptr, nullptr);

  edge_fused<<<FB2, 256, 0, stream>>>(ehc, srcs, row_start, WtK2, WtV2,
                                      qA, kvB, XM + 384);

  mfma_gemm<12, true, true><<<dim3(GB, 1), 256, 0, stream>>>(
      XM, Wt4, km4, W2b, nullptr, nullptr, h1, nullptr, nullptr,
      ln_g, ln_b, gate_w, gate_b, logit);

  // readout (gstart computed in-kernel)
  readout_kernel<<<GG, 128, 0, stream>>>(h1, logit, gid, out);
}

// Round 16
// 546.213 us; speedup vs baseline: 1.1090x; 1.0337x over previous
//
#include <hip/hip_runtime.h>
#include <math.h>

#define NN   20000      // nodes
#define NE   640000     // edges
#define NPADN 20480     // padded node count for scan (multiple of 4096)
#define HH   128        // hidden
#define GG   64         // groups
#define INF_ 1e30f
#define FB2  4096       // persistent blocks for edge_fused

typedef unsigned short u16;
typedef short bf16x8 __attribute__((ext_vector_type(8)));
typedef float f32x4 __attribute__((ext_vector_type(4)));

struct KMap { int colb[12]; };   // XM column base per 32-wide k-block
struct WEnt { const float* W; u16* dst; int K; int skip_at; int skip_amt; };
struct WTab { WEnt e[12]; };

__device__ __forceinline__ u16 f2bf(float x) {
  union { float f; unsigned u; } c; c.f = x;
  unsigned r = c.u + 0x7FFFu + ((c.u >> 16) & 1u);
  return (u16)(r >> 16);
}
__device__ __forceinline__ float bflo(unsigned w) {
  union { unsigned u; float f; } c; c.u = w << 16; return c.f;
}
__device__ __forceinline__ float bfhi(unsigned w) {
  union { unsigned u; float f; } c; c.u = w & 0xFFFF0000u; return c.f;
}

// ---------------- block reduction helpers (blockDim == 128) ----------------
__device__ __forceinline__ float blk_sum(float v, float* red) {
#pragma unroll
  for (int off = 32; off >= 1; off >>= 1) v += __shfl_xor(v, off);
  if ((threadIdx.x & 63) == 0) red[threadIdx.x >> 6] = v;
  __syncthreads();
  float r = red[0] + red[1];
  __syncthreads();
  return r;
}
__device__ __forceinline__ float blk_max(float v, float* red) {
#pragma unroll
  for (int off = 32; off >= 1; off >>= 1) v = fmaxf(v, __shfl_xor(v, off));
  if ((threadIdx.x & 63) == 0) red[threadIdx.x >> 6] = v;
  __syncthreads();
  float r = fmaxf(red[0], red[1]);
  __syncthreads();
  return r;
}

// ---------------- CSR construction ----------------
__global__ void zero_ints(int* p, int n) {
  int i = blockIdx.x * 256 + threadIdx.x;
  if (i < n) p[i] = 0;
}

__global__ void hist_kernel(const int* __restrict__ dst, int* __restrict__ deg) {
  int e = blockIdx.x * 256 + threadIdx.x;
  if (e < NE) atomicAdd(&deg[dst[e]], 1);
}

__global__ void scan_kernel(const int* __restrict__ deg, int* __restrict__ row_start,
                            int* __restrict__ cursor) {
  __shared__ int buf[256];
  __shared__ int carry_s;
  int t = threadIdx.x;
  if (t == 0) carry_s = 0;
  __syncthreads();
  for (int base = 0; base < NPADN; base += 4096) {
    int idx0 = base + t * 16;
    int4 a = *(const int4*)&deg[idx0];
    int4 b = *(const int4*)&deg[idx0 + 4];
    int4 c = *(const int4*)&deg[idx0 + 8];
    int4 d = *(const int4*)&deg[idx0 + 12];
    int x[16] = {a.x,a.y,a.z,a.w, b.x,b.y,b.z,b.w, c.x,c.y,c.z,c.w, d.x,d.y,d.z,d.w};
    int pre[16];
    int run = 0;
#pragma unroll
    for (int j = 0; j < 16; j++) { pre[j] = run; run += x[j]; }
    buf[t] = run;
    __syncthreads();
    int sum = run;
#pragma unroll
    for (int off = 1; off < 256; off <<= 1) {
      int addv = (t >= off) ? buf[t - off] : 0;
      __syncthreads();
      sum += addv;
      buf[t] = sum;
      __syncthreads();
    }
    int excl = sum - run;
    int carry = carry_s;
    int basev = carry + excl;
#pragma unroll
    for (int j = 0; j < 16; j++) {
      int i = idx0 + j;
      if (i < NN) { row_start[i] = basev + pre[j]; cursor[i] = basev + pre[j]; }
    }
    __syncthreads();
    if (t == 255) carry_s = carry + sum;
    __syncthreads();
  }
  if (t == 0) row_start[NN] = carry_s;
}

// pos[e] = CSR slot of edge e; srcs[p] = src node at CSR slot p
__global__ void scatter_kernel(const int* __restrict__ dst, const int* __restrict__ src,
                               int* __restrict__ cursor, int* __restrict__ pos,
                               int* __restrict__ srcs) {
  int e = blockIdx.x * 256 + threadIdx.x;
  if (e < NE) {
    int d = dst[e];
    int p = atomicAdd(&cursor[d], 1);
    pos[e] = p;
    srcs[p] = src[e];
  }
}

// ---------------- fused prepack: XM | ehc (CSR-scattered write) | 12 weight packs ----------------
__global__ __launch_bounds__(256) void pack_all(
    const float* __restrict__ kind, const float* __restrict__ ntype,
    const float* __restrict__ eh, const int* __restrict__ pos,
    u16* __restrict__ XM, u16* __restrict__ ehc, WTab wt) {
  int id = blockIdx.x * 256 + threadIdx.x;
  if (id < NN * 128) {                      // XM[:,0:128] = bf16([kind|ntype])
    int n = id >> 7, c = id & 127;
    float v = (c < 64) ? kind[n * 64 + c] : ntype[n * 64 + (c - 64)];
    XM[(size_t)n * 512 + c] = f2bf(v);
    return;
  }
  id -= NN * 128;
  if (id < NE * 8) {                        // ehc[pos[e]] = bf16(eh[e])
    int e = id >> 3, l = id & 7;
    const float* r = eh + (size_t)e * 64 + l * 8;
    float4 a = *(const float4*)r;
    float4 b = *(const float4*)(r + 4);
    union { u16 u[8]; uint4 v; } pk;
    pk.u[0] = f2bf(a.x); pk.u[1] = f2bf(a.y); pk.u[2] = f2bf(a.z); pk.u[3] = f2bf(a.w);
    pk.u[4] = f2bf(b.x); pk.u[5] = f2bf(b.y); pk.u[6] = f2bf(b.z); pk.u[7] = f2bf(b.w);
    int p = pos[e];
    *(uint4*)&ehc[(size_t)p * 64 + l * 8] = pk.v;
    return;
  }
  id -= NE * 8;
#pragma unroll 1
  for (int t = 0; t < 12; t++) {            // Wt[c][k] = bf16(W[rowmap(k)][c])
    int n = 128 * wt.e[t].K;
    if (id < n) {
      int K = wt.e[t].K;
      int c = id / K, k = id - c * K;
      int row = (k < wt.e[t].skip_at) ? k : k + wt.e[t].skip_amt;
      wt.e[t].dst[id] = f2bf(wt.e[t].W[row * 128 + c]);
      return;
    }
    id -= n;
  }
}

// ---------------- MFMA node GEMM (1 wave / 16 rows; chunk-split over blockIdx.y) ----------------
// Waves share nothing (no LDS), so 64-thread blocks quadruple schedulable
// units: grid 1250 vs 313 -> ~5 blocks/CU instead of 1.2 (the LN launches
// with chunk-count 1 were TLP-starved).
template <int KSTEPS, bool DO_LN, bool DO_LOGIT>
__global__ __launch_bounds__(64) void mfma_gemm(
    const u16* __restrict__ XM, const u16* __restrict__ Wt, KMap kmap,
    const float* __restrict__ b0, const float* __restrict__ b1, const float* __restrict__ b2,
    float* __restrict__ o0, u16* __restrict__ kvB, u16* __restrict__ outbf,
    const float* __restrict__ ln_g, const float* __restrict__ ln_b,
    const float* __restrict__ gate_w, const float* __restrict__ gate_b,
    float* __restrict__ logit) {
  const int lane = threadIdx.x;
  const int er = lane & 15, kg = lane >> 4;
  const int row0 = blockIdx.x * 16;
  if (row0 >= NN) return;
  const int chunk = blockIdx.y;
  const int arow = (row0 + er < NN) ? row0 + er : NN - 1;
  constexpr int K = KSTEPS * 32;
  const u16* aptr = XM + (size_t)arow * 512 + kg * 8;
  const u16* wptr = Wt + (size_t)chunk * 128 * K + (size_t)er * K + kg * 8;

  f32x4 acc[8];
#pragma unroll
  for (int i = 0; i < 8; i++) acc[i] = (f32x4){0.f, 0.f, 0.f, 0.f};

#pragma unroll
  for (int ks = 0; ks < KSTEPS; ks++) {
    bf16x8 a = *(const bf16x8*)&aptr[kmap.colb[ks]];
#pragma unroll
    for (int nt = 0; nt < 8; nt++) {
      bf16x8 b = *(const bf16x8*)&wptr[(size_t)nt * 16 * K + ks * 32];
      acc[nt] = __builtin_amdgcn_mfma_f32_16x16x32_bf16(a, b, acc[nt], 0, 0, 0);
    }
  }

  if (!DO_LN) {
    const float* bp = (chunk == 0) ? b0 : (chunk == 1) ? b1 : b2;
#pragma unroll
    for (int t = 0; t < 8; t++) {
      int col = er + 16 * t;
      float bv = bp[col];
#pragma unroll
      for (int r = 0; r < 4; r++) {
        int m = row0 + kg * 4 + r;
        if (m < NN) {
          float val = acc[t][r] + bv;
          if (chunk == 0) o0[(size_t)m * 128 + col] = val;
          else            kvB[(size_t)m * 256 + 2 * col + (chunk - 1)] = f2bf(val);
        }
      }
    }
  } else {
    float g[8], bb[8], gw[8];
#pragma unroll
    for (int t = 0; t < 8; t++) {
      int col = er + 16 * t;
      float bv = b0[col];
#pragma unroll
      for (int r = 0; r < 4; r++) acc[t][r] += bv;
      g[t] = ln_g[col]; bb[t] = ln_b[col];
      if (DO_LOGIT) gw[t] = gate_w[col];
    }
    float gb0 = DO_LOGIT ? gate_b[0] : 0.f;
#pragma unroll
    for (int r = 0; r < 4; r++) {
      float s = 0.f;
#pragma unroll
      for (int t = 0; t < 8; t++) s += acc[t][r];
#pragma unroll
      for (int off = 1; off <= 8; off <<= 1) s += __shfl_xor(s, off);
      float mean = s * (1.0f / 128.0f);
      float v = 0.f;
#pragma unroll
      for (int t = 0; t < 8; t++) { float d = acc[t][r] - mean; v = fmaf(d, d, v); }
#pragma unroll
      for (int off = 1; off <= 8; off <<= 1) v += __shfl_xor(v, off);
      float rstd = 1.0f / sqrtf(v * (1.0f / 128.0f) + 1e-5f);
      int m = row0 + kg * 4 + r;
      float lg = 0.f;
      float hv[8];
#pragma unroll
      for (int t = 0; t < 8; t++) {
        hv[t] = (acc[t][r] - mean) * rstd * g[t] + bb[t];
        if (DO_LOGIT) lg = fmaf(hv[t], gw[t], lg);
      }
      if (m < NN) {
        if (outbf) {
#pragma unroll
          for (int t = 0; t < 8; t++) outbf[(size_t)m * 512 + er + 16 * t] = f2bf(hv[t]);
        } else {
#pragma unroll
          for (int t = 0; t < 8; t++) o0[(size_t)m * 128 + er + 16 * t] = hv[t];
        }
      }
      if (DO_LOGIT) {
#pragma unroll
        for (int off = 1; off <= 8; off <<= 1) lg += __shfl_xor(lg, off);
        if (er == 0 && m < NN) logit[m] = lg + gb0;
      }
    }
  }
}

// ---------------- fused edge projection + softmax, 3-deep pipeline ----------------
// r14/r15-verified structure (149us, VGPR 84): ehc is CSR-ordered so PEHB's
// address is pure ALU — sequential per-node stream; only the kv gather is
// random. srcs is a plain int array.
#define PIDX(S, t_) { \
    int pp = rs + (t_) * 16 + er; \
    int lv = (pp < re) ? 1 : 0; \
    int pq = lv ? pp : re - 1; \
    pcv##S = pq < 0 ? 0 : pq; \
    pmN##S = lv ? 1.f : 0.f; \
    srcv##S = srcs[pcv##S]; }

#define PEHB(S) { \
    const u16* ep_ = ehc + (size_t)pcv##S * 64 + kg * 8; \
    bE0##S = *(const bf16x8*)&ep_[0]; \
    bE1##S = *(const bf16x8*)&ep_[32]; }

#define PGKV(S) { \
    const u16* kp_ = kvb + (size_t)srcv##S * 256 + 2 * cbase; \
    kv0##S = *(const uint4*)&kp_[0]; \
    kv1##S = *(const uint4*)&kp_[32]; }

#define PCOMP(S) { \
    f32x4 cK0 = {0.f,0.f,0.f,0.f}, cK1 = {0.f,0.f,0.f,0.f}; \
    f32x4 cV0 = {0.f,0.f,0.f,0.f}, cV1 = {0.f,0.f,0.f,0.f}; \
    cK0 = __builtin_amdgcn_mfma_f32_16x16x32_bf16(aK00, bE0##S, cK0, 0, 0, 0); \
    cK0 = __builtin_amdgcn_mfma_f32_16x16x32_bf16(aK01, bE1##S, cK0, 0, 0, 0); \
    cK1 = __builtin_amdgcn_mfma_f32_16x16x32_bf16(aK10, bE0##S, cK1, 0, 0, 0); \
    cK1 = __builtin_amdgcn_mfma_f32_16x16x32_bf16(aK11, bE1##S, cK1, 0, 0, 0); \
    cV0 = __builtin_amdgcn_mfma_f32_16x16x32_bf16(aV00, bE0##S, cV0, 0, 0, 0); \
    cV0 = __builtin_amdgcn_mfma_f32_16x16x32_bf16(aV01, bE1##S, cV0, 0, 0, 0); \
    cV1 = __builtin_amdgcn_mfma_f32_16x16x32_bf16(aV10, bE0##S, cV1, 0, 0, 0); \
    cV1 = __builtin_amdgcn_mfma_f32_16x16x32_bf16(aV11, bE1##S, cV1, 0, 0, 0); \
    float pm = pmC##S; \
    float kk, vv, pe; \
    kk = bflo(kv0##S.x) + cK0[0]; vv = bfhi(kv0##S.x) + cV0[0]; \
    pe = __expf(q0v.x * kk) * pm; S0[0] += pe; H0[0] = fmaf(pe, vv, H0[0]); \
    kk = bflo(kv0##S.y) + cK0[1]; vv = bfhi(kv0##S.y) + cV0[1]; \
    pe = __expf(q0v.y * kk) * pm; S0[1] += pe; H0[1] = fmaf(pe, vv, H0[1]); \
    kk = bflo(kv0##S.z) + cK0[2]; vv = bfhi(kv0##S.z) + cV0[2]; \
    pe = __expf(q0v.z * kk) * pm; S0[2] += pe; H0[2] = fmaf(pe, vv, H0[2]); \
    kk = bflo(kv0##S.w) + cK0[3]; vv = bfhi(kv0##S.w) + cV0[3]; \
    pe = __expf(q0v.w * kk) * pm; S0[3] += pe; H0[3] = fmaf(pe, vv, H0[3]); \
    kk = bflo(kv1##S.x) + cK1[0]; vv = bfhi(kv1##S.x) + cV1[0]; \
    pe = __expf(q1v.x * kk) * pm; S1[0] += pe; H1[0] = fmaf(pe, vv, H1[0]); \
    kk = bflo(kv1##S.y) + cK1[1]; vv = bfhi(kv1##S.y) + cV1[1]; \
    pe = __expf(q1v.y * kk) * pm; S1[1] += pe; H1[1] = fmaf(pe, vv, H1[1]); \
    kk = bflo(kv1##S.z) + cK1[2]; vv = bfhi(kv1##S.z) + cV1[2]; \
    pe = __expf(q1v.z * kk) * pm; S1[2] += pe; H1[2] = fmaf(pe, vv, H1[2]); \
    kk = bflo(kv1##S.w) + cK1[3]; vv = bfhi(kv1##S.w) + cV1[3]; \
    pe = __expf(q1v.w * kk) * pm; S1[3] += pe; H1[3] = fmaf(pe, vv, H1[3]); }

__global__ __launch_bounds__(256, 3) void edge_fused(
    const u16* __restrict__ ehc, const int* __restrict__ srcs,
    const int* __restrict__ row_start,
    const u16* __restrict__ WtK, const u16* __restrict__ WtV,
    const float* __restrict__ qn, const u16* __restrict__ kvb,
    u16* __restrict__ xmh) {
  const int lane = threadIdx.x & 63;
  const int qw = threadIdx.x >> 6;       // channel quarter 0..3
  const int er = lane & 15, kg = lane >> 4;
  const int cbase = qw * 32 + kg * 4;

  // weight A-fragments (round-2-validated layout)
  bf16x8 aK00, aK01, aK10, aK11, aV00, aV01, aV10, aV11;
  {
    int r0 = (qw * 2 + 0) * 16 + er;
    int r1 = (qw * 2 + 1) * 16 + er;
    aK00 = *(const bf16x8*)&WtK[r0 * 64 + kg * 8];
    aK01 = *(const bf16x8*)&WtK[r0 * 64 + 32 + kg * 8];
    aK10 = *(const bf16x8*)&WtK[r1 * 64 + kg * 8];
    aK11 = *(const bf16x8*)&WtK[r1 * 64 + 32 + kg * 8];
    aV00 = *(const bf16x8*)&WtV[r0 * 64 + kg * 8];
    aV01 = *(const bf16x8*)&WtV[r0 * 64 + 32 + kg * 8];
    aV10 = *(const bf16x8*)&WtV[r1 * 64 + kg * 8];
    aV11 = *(const bf16x8*)&WtV[r1 * 64 + 32 + kg * 8];
  }

  for (int n = blockIdx.x; n < NN; n += FB2) {
    const int rs = row_start[n], re = row_start[n + 1];
    const int T2 = (re - rs + 15) >> 4;
    float4 q0v = *(const float4*)&qn[(size_t)n * 128 + cbase];
    float4 q1v = *(const float4*)&qn[(size_t)n * 128 + cbase + 16];
    f32x4 S0 = {0.f,0.f,0.f,0.f}, S1 = {0.f,0.f,0.f,0.f};
    f32x4 H0 = {0.f,0.f,0.f,0.f}, H1 = {0.f,0.f,0.f,0.f};

    int pcvX, srcvX, pcvY, srcvY, pcvZ, srcvZ;
    float pmNX, pmCX, pmNY, pmCY, pmNZ, pmCZ;
    bf16x8 bE0X, bE1X, bE0Y, bE1Y, bE0Z, bE1Z;
    uint4 kv0X, kv1X, kv0Y, kv1Y, kv0Z, kv1Z;

    // prologue: tiles 0,1,2
    PIDX(X, 0); pmCX = pmNX; PEHB(X); PGKV(X);
    PIDX(Y, 1); pmCY = pmNY; PEHB(Y); PGKV(Y);
    PIDX(Z, 2); pmCZ = pmNZ; PEHB(Z); PGKV(Z);

    for (int t = 0; t < T2; t += 3) {
      PIDX(X, t + 3); PCOMP(X); pmCX = pmNX; PEHB(X); PGKV(X);
      PIDX(Y, t + 4); PCOMP(Y); pmCY = pmNY; PEHB(Y); PGKV(Y);
      PIDX(Z, t + 5); PCOMP(Z); pmCZ = pmNZ; PEHB(Z); PGKV(Z);
    }

    // reduce over the 16 er-lanes
#pragma unroll
    for (int off = 1; off <= 8; off <<= 1) {
#pragma unroll
      for (int j = 0; j < 4; j++) {
        S0[j] += __shfl_xor(S0[j], off);
        H0[j] += __shfl_xor(H0[j], off);
        S1[j] += __shfl_xor(S1[j], off);
        H1[j] += __shfl_xor(H1[j], off);
      }
    }
    if (er == 0) {
      uint2 p0, p1;
      if (re > rs) {
        p0.x = (unsigned)f2bf(H0[0]/S0[0]) | ((unsigned)f2bf(H0[1]/S0[1]) << 16);
        p0.y = (unsigned)f2bf(H0[2]/S0[2]) | ((unsigned)f2bf(H0[3]/S0[3]) << 16);
        p1.x = (unsigned)f2bf(H1[0]/S1[0]) | ((unsigned)f2bf(H1[1]/S1[1]) << 16);
        p1.y = (unsigned)f2bf(H1[2]/S1[2]) | ((unsigned)f2bf(H1[3]/S1[3]) << 16);
      } else { p0.x = p0.y = p1.x = p1.y = 0u; }
      *(uint2*)&xmh[(size_t)n * 512 + cbase] = p0;
      *(uint2*)&xmh[(size_t)n * 512 + cbase + 16] = p1;
    }
  }
}

// ---------------- readout (gstart folded in via binary search) ----------------
__global__ __launch_bounds__(128) void readout_kernel(
    const float* __restrict__ h1, const float* __restrict__ logit,
    const int* __restrict__ gid, float* __restrict__ out) {
  __shared__ float red[2];
  int g = blockIdx.x, tid = threadIdx.x;
  int s0, s1;
  {
    int lo = 0, hi = NN;                       // first i with gid[i] >= g
    while (lo < hi) { int mid = (lo + hi) >> 1; if (gid[mid] < g) lo = mid + 1; else hi = mid; }
    s0 = lo;
    lo = s0; hi = NN;                          // first i with gid[i] >= g+1
    while (lo < hi) { int mid = (lo + hi) >> 1; if (gid[mid] < g + 1) lo = mid + 1; else hi = mid; }
    s1 = lo;
  }

  float mx = -INF_;
  for (int i = s0 + tid; i < s1; i += 128) mx = fmaxf(mx, logit[i]);
  mx = blk_max(mx, red);

  float sum = 0.0f;
  for (int i = s0 + tid; i < s1; i += 128) sum += __expf(logit[i] - mx);
  sum = blk_sum(sum, red);

  float a0 = 0.f, a1 = 0.f, a2 = 0.f, a3 = 0.f;
  int i = s0;
  for (; i + 4 <= s1; i += 4) {
    float w0 = __expf(logit[i + 0] - mx);
    float w1 = __expf(logit[i + 1] - mx);
    float w2 = __expf(logit[i + 2] - mx);
    float w3 = __expf(logit[i + 3] - mx);
    a0 = fmaf(w0, h1[(size_t)(i + 0) * 128 + tid], a0);
    a1 = fmaf(w1, h1[(size_t)(i + 1) * 128 + tid], a1);
    a2 = fmaf(w2, h1[(size_t)(i + 2) * 128 + tid], a2);
    a3 = fmaf(w3, h1[(size_t)(i + 3) * 128 + tid], a3);
  }
  for (; i < s1; i++) {
    float w = __expf(logit[i] - mx);
    a0 = fmaf(w, h1[(size_t)i * 128 + tid], a0);
  }
  float acc = (a0 + a1) + (a2 + a3);
  out[g * 128 + tid] = (s1 > s0) ? (acc / sum) : 0.0f;
}

// ---------------- launcher ----------------
extern "C" void kernel_launch(void* const* d_in, const int* in_sizes, int n_in,
                              void* d_out, int out_size, void* d_ws, size_t ws_size,
                              hipStream_t stream) {
  const float* kind  = (const float*)d_in[0];
  const float* ntype = (const float*)d_in[1];
  const float* eh    = (const float*)d_in[2];
  const float* Qw = (const float*)d_in[3];  const float* Qb = (const float*)d_in[4];
  const float* Kw = (const float*)d_in[5];  const float* Kb = (const float*)d_in[6];
  const float* Vw = (const float*)d_in[7];  const float* Vb = (const float*)d_in[8];
  const float* Ww = (const float*)d_in[9];  const float* Wb = (const float*)d_in[10];
  const float* Q2w = (const float*)d_in[11]; const float* Q2b = (const float*)d_in[12];
  const float* K2w = (const float*)d_in[13]; const float* K2b = (const float*)d_in[14];
  const float* V2w = (const float*)d_in[15]; const float* V2b = (const float*)d_in[16];
  const float* W2w = (const float*)d_in[17]; const float* W2b = (const float*)d_in[18];
  const float* ln_g = (const float*)d_in[19]; const float* ln_b = (const float*)d_in[20];
  const float* gate_w = (const float*)d_in[21]; const float* gate_b = (const float*)d_in[22];
  const int* src = (const int*)d_in[23];
  const int* dst = (const int*)d_in[24];
  const int* gid = (const int*)d_in[25];
  float* out = (float*)d_out;

  char* wp = (char*)d_ws;
  auto alloc = [&](size_t bytes) {
    void* p = (void*)wp;
    wp += (bytes + 255) & ~(size_t)255;
    return p;
  };
  u16* XM  = (u16*)alloc((size_t)NN * 512 * 2);   // [kind|ntype | hn | h | hn2] bf16
  u16* ehc = (u16*)alloc((size_t)NE * 64 * 2);    // CSR-order bf16 eh
  float* qA = (float*)alloc((size_t)NN * HH * 4);
  u16* kvB = (u16*)alloc((size_t)NN * 256 * 2);   // interleaved k/v bf16
  float* h1 = (float*)alloc((size_t)NN * HH * 4);
  float* logit = (float*)alloc((size_t)NN * 4);
  u16* Wt1 = (u16*)alloc((size_t)384 * 128 * 2);
  u16* Wt2 = (u16*)alloc((size_t)128 * 256 * 2);
  u16* Wt3 = (u16*)alloc((size_t)384 * 256 * 2);
  u16* Wt4 = (u16*)alloc((size_t)128 * 384 * 2);
  u16* WtK1 = (u16*)alloc((size_t)128 * 64 * 2);
  u16* WtV1 = (u16*)alloc((size_t)128 * 64 * 2);
  u16* WtK2 = (u16*)alloc((size_t)128 * 64 * 2);
  u16* WtV2 = (u16*)alloc((size_t)128 * 64 * 2);
  int* deg       = (int*)alloc((size_t)NPADN * 4);
  int* row_start = (int*)alloc((size_t)(NN + 1) * 4);
  int* cursor    = (int*)alloc((size_t)NN * 4);
  int* pos       = (int*)alloc((size_t)NE * 4);
  int* srcs      = (int*)alloc((size_t)NE * 4);

  const int NB = 1 << 30;  // no skip

  // CSR
  zero_ints<<<(NPADN + 255) / 256, 256, 0, stream>>>(deg, NPADN);
  hist_kernel<<<(NE + 255) / 256, 256, 0, stream>>>(dst, deg);
  scan_kernel<<<1, 256, 0, stream>>>(deg, row_start, cursor);
  scatter_kernel<<<(NE + 255) / 256, 256, 0, stream>>>(dst, src, cursor, pos, srcs);

  // fused prepack (XM, CSR-scattered ehc, all weight transposes)
  WTab wt;
  wt.e[0]  = {Qw,             Wt1,                 128, NB, 0};
  wt.e[1]  = {Kw,             Wt1 + 128 * 128,     128, NB, 0};
  wt.e[2]  = {Vw,             Wt1 + 2 * 128 * 128, 128, NB, 0};
  wt.e[3]  = {Ww,             Wt2,                 256, NB, 0};
  wt.e[4]  = {Q2w,            Wt3,                 256, NB, 0};
  wt.e[5]  = {K2w,            Wt3 + 128 * 256,     256, 128, 64};
  wt.e[6]  = {V2w,            Wt3 + 2 * 128 * 256, 256, 128, 64};
  wt.e[7]  = {W2w,            Wt4,                 384, NB, 0};
  wt.e[8]  = {Kw + 128 * 128, WtK1,                64,  NB, 0};
  wt.e[9]  = {Vw + 128 * 128, WtV1,                64,  NB, 0};
  wt.e[10] = {K2w + 128 * 128, WtK2,               64,  NB, 0};
  wt.e[11] = {V2w + 128 * 128, WtV2,               64,  NB, 0};
  const long long PACK_ITEMS = (long long)NN * 128 + (long long)NE * 8 + 262144;
  pack_all<<<(int)((PACK_ITEMS + 255) / 256), 256, 0, stream>>>(
      kind, ntype, eh, pos, XM, ehc, wt);

  KMap km1{}, km2{}, km3{}, km4{};
  for (int b = 0; b < 4; b++)  km1.colb[b] = 32 * b;                       // [kind|ntype]
  for (int b = 0; b < 8; b++)  km2.colb[b] = (b < 4) ? 128 + 32 * b : 32 * (b - 4);   // [hn | kind|ntype]
  for (int b = 0; b < 8; b++)  km3.colb[b] = (b < 4) ? 32 * b : 256 + 32 * (b - 4);   // [kind|ntype | h]
  for (int b = 0; b < 12; b++) km4.colb[b] = (b < 4) ? 384 + 32 * b
                                       : (b < 8) ? 256 + 32 * (b - 4) : 32 * (b - 8); // [hn2 | h | kind|ntype]

  const int GB = (NN + 15) / 16;   // 1250 one-wave blocks

  // ---- layer 1 ----
  mfma_gemm<4, false, false><<<dim3(GB, 3), 64, 0, stream>>>(
      XM, Wt1, km1, Qb, Kb, Vb, qA, kvB, nullptr,
      nullptr, nullptr, nullptr, nullptr, nullptr);

  edge_fused<<<FB2, 256, 0, stream>>>(ehc, srcs, row_start, WtK1, WtV1,
                                      qA, kvB, XM + 128);

  mfma_gemm<8, true, false><<<dim3(GB, 1), 64, 0, stream>>>(
      XM, Wt2, km2, Wb, nullptr, nullptr, nullptr, nullptr, XM + 256,
      ln_g, ln_b, nullptr, nullptr, nullptr);

  // ---- layer 2 ----
  mfma_gemm<8, false, false><<<dim3(GB, 3), 64, 0, stream>>>(
      XM, Wt3, km3, Q2b, K2b, V2b, qA, kvB, nullptr,
      nullptr, nullptr, nullptr, nullptr, nullptr);

  edge_fused<<<FB2, 256, 0, stream>>>(ehc, srcs, row_start, WtK2, WtV2,
                                      qA, kvB, XM + 384);

  mfma_gemm<12, true, true><<<dim3(GB, 1), 64, 0, stream>>>(
      XM, Wt4, km4, W2b, nullptr, nullptr, h1, nullptr, nullptr,
      ln_g, ln_b, gate_w, gate_b, logit);

  // readout (gstart computed in-kernel)
  readout_kernel<<<GG, 128, 0, stream>>>(h1, logit, gid, out);
}